// Round 4
// baseline (384.486 us; speedup 1.0000x reference)
//
#include <hip/hip_runtime.h>

#define H 512
#define W 512
#define TILE 32
#define NT 256
#define BW 68                 // LDS row stride (floats): 16B-aligned, bank-spread
#define BROWS 58
#define BUFSZ (BROWS * BW)    // 3944 floats = 15776 B per buffer
#define TPD (W / TILE)        // 16 tiles per dim
#define NBANKS 16
#define BANK_STRIDE 16
// Tile pixel (y,x) at LDS (13+y, 16+x). Staging clamp-replicates true image
// borders; replication is invariant under erode (monotone min argument), so
// only dilate at border blocks needs a per-iteration guard clone (rows 12/45,
// cols 15/48).

__device__ __forceinline__ float sigmf(float x) {
  return 1.0f / (1.0f + __expf(-x));
}
__device__ __forceinline__ float min3f(float a, float b, float c) {
  return fminf(fminf(a, b), c);
}
__device__ __forceinline__ float max3f(float a, float b, float c) {
  return fmaxf(fmaxf(a, b), c);
}
__device__ __forceinline__ float4 ld4(const float* p) { return *(const float4*)p; }
__device__ __forceinline__ void st4(float* p, float4 v) { *(float4*)p = v; }
__device__ __forceinline__ float4 min34(float4 a, float4 b, float4 c) {
  float4 o;
  o.x = min3f(a.x, b.x, c.x); o.y = min3f(a.y, b.y, c.y);
  o.z = min3f(a.z, b.z, c.z); o.w = min3f(a.w, b.w, c.w);
  return o;
}
__device__ __forceinline__ float4 max34(float4 a, float4 b, float4 c) {
  float4 o;
  o.x = max3f(a.x, b.x, c.x); o.y = max3f(a.y, b.y, c.y);
  o.z = max3f(a.z, b.z, c.z); o.w = max3f(a.w, b.w, c.w);
  return o;
}

__global__ __launch_bounds__(NT, 5) void cl_skel_kernel(
    const float* __restrict__ pred, const float* __restrict__ target,
    double* __restrict__ sums) {
  __shared__ float buf0[BUFSZ];
  __shared__ float buf1[BUFSZ];
  __shared__ float rbuf[2][NT / 64];

  const int tid = threadIdx.x;
  const int tileIdx = blockIdx.x;
  const int batch = blockIdx.y;
  const bool isPred = (blockIdx.z == 0);
  const int tr = (tileIdx / TPD) * TILE;
  const int tc = (tileIdx % TPD) * TILE;
  const float* __restrict__ img = isPred ? pred : target;
  const float* __restrict__ other = isPred ? target : pred;
  const size_t base = (size_t)batch * (H * W);

  const bool top = (tr == 0), lft = (tc == 0);
  const bool bot = (tr == H - TILE), rgt = (tc == W - TILE);
  const bool border = top | lft | bot | rgt;

  // ---- Stage x0: rows 0..57, cols 0..63 (clamped => border replication) ----
  if (!border) {
    for (int it = tid; it < BROWS * 16; it += NT) {
      int row = it >> 4, g = it & 15;
      int gr = tr - 13 + row;
      int gc = tc - 16 + 4 * g;
      float4 v = ld4(&img[base + (size_t)gr * W + gc]);
      if (isPred) {
        v.x = sigmf(v.x); v.y = sigmf(v.y); v.z = sigmf(v.z); v.w = sigmf(v.w);
      }
      st4(&buf0[row * BW + 4 * g], v);
    }
  } else {
    for (int it = tid; it < BROWS * 16; it += NT) {
      int row = it >> 4, g = it & 15;
      int gr = min(max(tr - 13 + row, 0), H - 1);
      int gc = tc - 16 + 4 * g;
      float4 v;
      v.x = img[base + (size_t)gr * W + min(max(gc + 0, 0), W - 1)];
      v.y = img[base + (size_t)gr * W + min(max(gc + 1, 0), W - 1)];
      v.z = img[base + (size_t)gr * W + min(max(gc + 2, 0), W - 1)];
      v.w = img[base + (size_t)gr * W + min(max(gc + 3, 0), W - 1)];
      if (isPred) {
        v.x = sigmf(v.x); v.y = sigmf(v.y); v.z = sigmf(v.z); v.w = sigmf(v.w);
      }
      st4(&buf0[row * BW + 4 * g], v);
    }
  }
  __syncthreads();

  const int ty = tid >> 3;  // 0..31: tile row / erode row-quad
  const int tg = tid & 7;   // 0..7 : tile col group / erode 8-col group
  const int ca = (13 + ty) * BW + 16 + 4 * tg;

  float4 skel = make_float4(0.0f, 0.0f, 0.0f, 0.0f);
  float* src = buf0;
  float* dst = buf1;

#pragma unroll 1
  for (int R = 11; R >= 1; --R) {
    float4 t0 = ld4(src + ca);  // x_k at own px (must be pre-barrier: src is
                                // overwritten by other threads' next erode)

    // ---- erode src->dst: rows [13-R,44+R], cols [cs, cs+8*G8n) ----
    const int rows4 = (35 + 2 * R) >> 2;
    const int cs = (15 - R) & ~7;
    const int G8n = ((48 + R - cs) >> 3) + 1;
    const int rb = 13 - R, re = 44 + R;
    if (ty < rows4 && tg < G8n) {
      const int c0 = cs + 8 * tg;
      const int r0 = rb + 4 * ty;
      float4 vA[6], vB[6];
#pragma unroll
      for (int k = 0; k < 6; ++k) {
        int rr = min(r0 - 1 + k, BROWS - 1);  // clamp: clamped reads feed only
        vA[k] = ld4(src + rr * BW + c0);      // masked-out rows
        vB[k] = ld4(src + rr * BW + c0 + 4);
      }
#pragma unroll
      for (int k = 0; k < 4; ++k) {
        int r = r0 + k;
        float4 vmA = min34(vA[k], vA[k + 1], vA[k + 2]);
        float4 vmB = min34(vB[k], vB[k + 1], vB[k + 2]);
        float4 cAv = vA[k + 1], cBv = vB[k + 1];
        float l = __shfl_up(cBv.w, 1, 8);    // wrong at g==0: garbage col only
        float rr2 = __shfl_down(cAv.x, 1, 8);  // wrong at g==G8n-1: col>=48+R
        if (r <= re) {
          float4 oA, oB;
          oA.x = fminf(vmA.x, fminf(l, cAv.y));
          oA.y = fminf(vmA.y, fminf(cAv.x, cAv.z));
          oA.z = fminf(vmA.z, fminf(cAv.y, cAv.w));
          oA.w = fminf(vmA.w, fminf(cAv.z, cBv.x));
          oB.x = fminf(vmB.x, fminf(cAv.w, cBv.y));
          oB.y = fminf(vmB.y, fminf(cBv.x, cBv.z));
          oB.z = fminf(vmB.z, fminf(cBv.y, cBv.w));
          oB.w = fminf(vmB.w, fminf(cBv.z, rr2));
          st4(dst + r * BW + c0, oA);
          st4(dst + r * BW + c0 + 4, oB);
        }
      }
    }
    __syncthreads();

    // ---- border guard clone (dilate needs exact clamp rows/cols) ----
    if (border) {
      int side = tid >> 6, p = tid & 63;
      if (side == 0 && top && p < 34) {
        int c = 15 + p;
        int sc = min(max(c, lft ? 16 : 15), rgt ? 47 : 48);
        dst[12 * BW + c] = dst[13 * BW + sc];
      } else if (side == 1 && bot && p < 34) {
        int c = 15 + p;
        int sc = min(max(c, lft ? 16 : 15), rgt ? 47 : 48);
        dst[45 * BW + c] = dst[44 * BW + sc];
      } else if (side == 2 && lft) {
        int r = (top ? 13 : 12) + p;
        if (r <= (bot ? 44 : 45)) dst[r * BW + 15] = dst[r * BW + 16];
      } else if (side == 3 && rgt) {
        int r = (top ? 13 : 12) + p;
        if (r <= (bot ? 44 : 45)) dst[r * BW + 48] = dst[r * BW + 47];
      }
      __syncthreads();
    }

    // ---- dilate(dst) at own 4 px; update skel (reads dst only) ----
    {
      float4 a = ld4(dst + ca - BW);
      float4 b = ld4(dst + ca);
      float4 c = ld4(dst + ca + BW);
      float4 vm = max34(a, b, c);
      float vl = __shfl_up(vm.w, 1, 8);
      float vr = __shfl_down(vm.x, 1, 8);
      if (tg == 0) {
        vl = max3f(dst[ca - BW - 1], dst[ca - 1], dst[ca + BW - 1]);  // col 15
      }
      if (tg == 7) {
        vr = max3f(dst[ca - BW + 4], dst[ca + 4], dst[ca + BW + 4]);  // col 48
      }
      float h0 = max3f(vl, vm.x, vm.y);
      float h1 = max3f(vm.x, vm.y, vm.z);
      float h2 = max3f(vm.y, vm.z, vm.w);
      float h3 = max3f(vm.z, vm.w, vr);
      float d0 = fmaxf(t0.x - h0, 0.0f);
      float d1 = fmaxf(t0.y - h1, 0.0f);
      float d2 = fmaxf(t0.z - h2, 0.0f);
      float d3 = fmaxf(t0.w - h3, 0.0f);
      skel.x += fmaxf(fmaf(-skel.x, d0, d0), 0.0f);
      skel.y += fmaxf(fmaf(-skel.y, d1, d1), 0.0f);
      skel.z += fmaxf(fmaf(-skel.z, d2, d2), 0.0f);
      skel.w += fmaxf(fmaf(-skel.w, d3, d3), 0.0f);
    }
    float* t = src; src = dst; dst = t;
    // no barrier: next erode writes only old-src, which no one reads anymore
  }

  // ---- Products with the other image over this thread's 4 tile px ----
  float4 o = ld4(&other[base + (size_t)(tr + ty) * W + tc + 4 * tg]);
  if (!isPred) {
    o.x = sigmf(o.x); o.y = sigmf(o.y); o.z = sigmf(o.z); o.w = sigmf(o.w);
  }
  float s0 = (skel.x + skel.y) + (skel.z + skel.w);
  float s1 = (skel.x * o.x + skel.y * o.y) + (skel.z * o.z + skel.w * o.w);

#pragma unroll
  for (int off = 32; off > 0; off >>= 1) {
    s0 += __shfl_down(s0, off, 64);
    s1 += __shfl_down(s1, off, 64);
  }
  const int wave = tid >> 6;
  const int lane = tid & 63;
  if (lane == 0) {
    rbuf[0][wave] = s0;
    rbuf[1][wave] = s1;
  }
  __syncthreads();
  if (tid == 0) {
    float t0 = 0.0f, t1 = 0.0f;
#pragma unroll
    for (int w = 0; w < NT / 64; ++w) {
      t0 += rbuf[0][w];
      t1 += rbuf[1][w];
    }
    const int bank = (int)(blockIdx.x & (NBANKS - 1));
    const int o2 = (isPred ? 0 : 2);
    atomicAdd(&sums[bank * BANK_STRIDE + o2], (double)t0);
    atomicAdd(&sums[bank * BANK_STRIDE + o2 + 1], (double)t1);
  }
}

__global__ void cl_finalize_kernel(const double* __restrict__ sums,
                                   float* __restrict__ out) {
  double s[4] = {0.0, 0.0, 0.0, 0.0};
  for (int b = 0; b < NBANKS; ++b)
    for (int j = 0; j < 4; ++j) s[j] += sums[b * BANK_STRIDE + j];
  double tprec = (s[1] + 1.0) / (s[0] + 1.0);
  double tsens = (s[3] + 1.0) / (s[2] + 1.0);
  double cl = 2.0 * tprec * tsens / (tprec + tsens + 1e-7);
  out[0] = (float)(1.0 - cl);
}

extern "C" void kernel_launch(void* const* d_in, const int* in_sizes, int n_in,
                              void* d_out, int out_size, void* d_ws,
                              size_t ws_size, hipStream_t stream) {
  const float* pred = (const float*)d_in[0];
  const float* target = (const float*)d_in[1];
  double* sums = (double*)d_ws;
  const int batch = in_sizes[0] / (H * W);  // 32

  hipMemsetAsync(d_ws, 0, NBANKS * BANK_STRIDE * sizeof(double), stream);
  dim3 grid(TPD * TPD, batch, 2);
  cl_skel_kernel<<<grid, NT, 0, stream>>>(pred, target, sums);
  cl_finalize_kernel<<<1, 1, 0, stream>>>(sums, (float*)d_out);
}

// Round 5
// 215.258 us; speedup vs baseline: 1.7862x; 1.7862x over previous
//
#include <hip/hip_runtime.h>

#define H 512
#define W 512
#define TILE 64
#define NT 256
#define SW 104                // LDS row stride in halfs (52 dwords, 20 banks)
#define SROWS 90
#define TPD (W / TILE)        // 8 tiles per dim
#define NBANKS 16
#define BANK_STRIDE 16
// Tile px (y,x) lives at LDS (13+y, 16+x) in half precision. Staging
// clamp-replicates true image borders; replication self-propagates through
// the erode chain (region shrinks 1 row/pass, matching contamination), so
// NO guard refresh is needed. Col 0/95 garbage from edge reads stays >=5
// cols outside the needed region for all 11 passes.

typedef _Float16 h8 __attribute__((ext_vector_type(8)));
typedef _Float16 h4 __attribute__((ext_vector_type(4)));

__device__ __forceinline__ float sigmf(float x) {
  return 1.0f / (1.0f + __expf(-x));
}
__device__ __forceinline__ float4 ld4(const float* p) { return *(const float4*)p; }

__device__ __forceinline__ h8 min3v(h8 a, h8 b, h8 c) {
  return __builtin_elementwise_min(__builtin_elementwise_min(a, b), c);
}
__device__ __forceinline__ h8 max3v(h8 a, h8 b, h8 c) {
  return __builtin_elementwise_max(__builtin_elementwise_max(a, b), c);
}
__device__ __forceinline__ h8 shl1(h8 v, _Float16 e) {
  h8 r = __builtin_shufflevector(v, v, 7, 0, 1, 2, 3, 4, 5, 6);
  r[0] = e;
  return r;
}
__device__ __forceinline__ h8 shr1(h8 v, _Float16 e) {
  h8 r = __builtin_shufflevector(v, v, 1, 2, 3, 4, 5, 6, 7, 0);
  r[7] = e;
  return r;
}
// b32 loads of half pairs (keeps ds_read2 mergeability), extract one half.
__device__ __forceinline__ _Float16 hi_half(const _Float16* p) {
  unsigned v = *(const unsigned*)p;
  unsigned short s = (unsigned short)(v >> 16);
  return __builtin_bit_cast(_Float16, s);
}
__device__ __forceinline__ _Float16 lo_half(const _Float16* p) {
  unsigned v = *(const unsigned*)p;
  return __builtin_bit_cast(_Float16, (unsigned short)v);
}
__device__ __forceinline__ _Float16 hmax3(_Float16 a, _Float16 b, _Float16 c) {
  _Float16 m = a > b ? a : b;
  return m > c ? m : c;
}

__global__ __launch_bounds__(NT) void cl_skel_kernel(
    const float* __restrict__ pred, const float* __restrict__ target,
    double* __restrict__ sums) {
  __shared__ _Float16 buf0[SROWS * SW];
  __shared__ _Float16 buf1[SROWS * SW];
  __shared__ float rbuf[2][NT / 64];

  const int tid = threadIdx.x;
  const int tileIdx = blockIdx.x;
  const int batch = blockIdx.y;
  const bool isPred = (blockIdx.z == 0);
  const int tr = (tileIdx / TPD) * TILE;
  const int tc = (tileIdx % TPD) * TILE;
  const float* __restrict__ img = isPred ? pred : target;
  const float* __restrict__ other = isPred ? target : pred;
  const size_t base = (size_t)batch * (H * W);

  const bool border = (tr == 0) | (tc == 0) | (tr == H - TILE) | (tc == W - TILE);

  // ---- Stage x0 (fp16): rows 0..89, half cols 0..95 (24 float4 groups) ----
  if (!border) {
    for (int it = tid; it < SROWS * 24; it += NT) {
      int row = it / 24, g = it - row * 24;
      int gr = tr - 13 + row;
      int gc = tc - 16 + 4 * g;
      float4 v = ld4(&img[base + (size_t)gr * W + gc]);
      if (isPred) {
        v.x = sigmf(v.x); v.y = sigmf(v.y); v.z = sigmf(v.z); v.w = sigmf(v.w);
      }
      h4 hv;
      hv[0] = (_Float16)v.x; hv[1] = (_Float16)v.y;
      hv[2] = (_Float16)v.z; hv[3] = (_Float16)v.w;
      *(h4*)(buf0 + row * SW + 4 * g) = hv;
    }
  } else {
    for (int it = tid; it < SROWS * 24; it += NT) {
      int row = it / 24, g = it - row * 24;
      int gr = min(max(tr - 13 + row, 0), H - 1);
      int gc = tc - 16 + 4 * g;
      float4 v;
      v.x = img[base + (size_t)gr * W + min(max(gc + 0, 0), W - 1)];
      v.y = img[base + (size_t)gr * W + min(max(gc + 1, 0), W - 1)];
      v.z = img[base + (size_t)gr * W + min(max(gc + 2, 0), W - 1)];
      v.w = img[base + (size_t)gr * W + min(max(gc + 3, 0), W - 1)];
      if (isPred) {
        v.x = sigmf(v.x); v.y = sigmf(v.y); v.z = sigmf(v.z); v.w = sigmf(v.w);
      }
      h4 hv;
      hv[0] = (_Float16)v.x; hv[1] = (_Float16)v.y;
      hv[2] = (_Float16)v.z; hv[3] = (_Float16)v.w;
      *(h4*)(buf0 + row * SW + 4 * g) = hv;
    }
  }
  __syncthreads();

  const int ty = tid >> 2;  // 0..63: own tile row
  const int tg = tid & 3;   // 0..3 : own 16-col group
  const int rr = 13 + ty;
  const int c0 = 16 + 16 * tg;

  h8 skelE = (h8)(_Float16)0.0f;
  h8 skelF = (h8)(_Float16)0.0f;
  _Float16* src = buf0;
  _Float16* dst = buf1;

#pragma unroll 1
  for (int R = 11; R >= 1; --R) {
    // t0 = x_k at own 16 px (pre-barrier read of src)
    const _Float16* ps = src + rr * SW + c0;
    h8 t0E = *(const h8*)ps;
    h8 t0F = *(const h8*)(ps + 8);

    // ---- erode src->dst: rows [13-R, 76+R] (row pairs), 12 groups/row ----
    const int rb = 13 - R;
    const int items = (32 + R) * 12;
    for (int it = tid; it < items; it += NT) {
      int rp = it / 12;
      int g = it - rp * 12;
      int r0 = rb + 2 * rp;
      const _Float16* s0 = src + (r0 - 1) * SW + 8 * g;
      h8 a = *(const h8*)(s0);
      h8 b = *(const h8*)(s0 + SW);
      h8 c = *(const h8*)(s0 + 2 * SW);
      h8 d = *(const h8*)(s0 + 3 * SW);
      _Float16 le0 = hi_half(s0 + SW - 2);
      _Float16 le1 = hi_half(s0 + 2 * SW - 2);
      _Float16 re0 = lo_half(s0 + SW + 8);
      _Float16 re1 = lo_half(s0 + 2 * SW + 8);
      h8 o0 = __builtin_elementwise_min(
          min3v(a, b, c),
          __builtin_elementwise_min(shl1(b, le0), shr1(b, re0)));
      h8 o1 = __builtin_elementwise_min(
          min3v(b, c, d),
          __builtin_elementwise_min(shl1(c, le1), shr1(c, re1)));
      *(h8*)(dst + r0 * SW + 8 * g) = o0;
      *(h8*)(dst + (r0 + 1) * SW + 8 * g) = o1;
    }
    __syncthreads();

    // ---- dilate(dst) at own 16 px; skel update (reads dst only) ----
    {
      const _Float16* pm = dst + (rr - 1) * SW + c0;
      h8 aE = *(const h8*)(pm),          aF = *(const h8*)(pm + 8);
      h8 bE = *(const h8*)(pm + SW),     bF = *(const h8*)(pm + SW + 8);
      h8 cE = *(const h8*)(pm + 2 * SW), cF = *(const h8*)(pm + 2 * SW + 8);
      _Float16 vl = hmax3(hi_half(pm - 2), hi_half(pm + SW - 2),
                          hi_half(pm + 2 * SW - 2));
      _Float16 vr = hmax3(lo_half(pm + 16), lo_half(pm + SW + 16),
                          lo_half(pm + 2 * SW + 16));
      h8 vmE = max3v(aE, bE, cE);
      h8 vmF = max3v(aF, bF, cF);
      h8 hE = max3v(shl1(vmE, vl), vmE, shr1(vmE, vmF[0]));
      h8 hF = max3v(shl1(vmF, vmE[7]), vmF, shr1(vmF, vr));
      h8 z = (h8)(_Float16)0.0f;
      h8 dE = __builtin_elementwise_max(t0E - hE, z);
      h8 dF = __builtin_elementwise_max(t0F - hF, z);
      skelE += __builtin_elementwise_max(dE - skelE * dE, z);
      skelF += __builtin_elementwise_max(dF - skelF * dF, z);
    }
    _Float16* t = src; src = dst; dst = t;
    // single barrier/iter: all src reads are pre-barrier; next erode writes
    // old-src only after the barrier; dilate + next t0/erode read dst only.
  }

  // ---- Products with the other image over own 16 px ----
  const float* orow = other + base + (size_t)(tr + ty) * W + tc + 16 * tg;
  float s0 = 0.0f, s1 = 0.0f;
#pragma unroll
  for (int q = 0; q < 4; ++q) {
    float4 o = ld4(orow + 4 * q);
    if (!isPred) {
      o.x = sigmf(o.x); o.y = sigmf(o.y); o.z = sigmf(o.z); o.w = sigmf(o.w);
    }
    float sk0, sk1, sk2, sk3;
    if (q < 2) {
      sk0 = (float)skelE[4 * q + 0]; sk1 = (float)skelE[4 * q + 1];
      sk2 = (float)skelE[4 * q + 2]; sk3 = (float)skelE[4 * q + 3];
    } else {
      sk0 = (float)skelF[4 * q - 8]; sk1 = (float)skelF[4 * q - 7];
      sk2 = (float)skelF[4 * q - 6]; sk3 = (float)skelF[4 * q - 5];
    }
    s0 += (sk0 + sk1) + (sk2 + sk3);
    s1 += (sk0 * o.x + sk1 * o.y) + (sk2 * o.z + sk3 * o.w);
  }

#pragma unroll
  for (int off = 32; off > 0; off >>= 1) {
    s0 += __shfl_down(s0, off, 64);
    s1 += __shfl_down(s1, off, 64);
  }
  const int wave = tid >> 6;
  const int lane = tid & 63;
  if (lane == 0) {
    rbuf[0][wave] = s0;
    rbuf[1][wave] = s1;
  }
  __syncthreads();
  if (tid == 0) {
    float t0 = 0.0f, t1 = 0.0f;
#pragma unroll
    for (int w = 0; w < NT / 64; ++w) {
      t0 += rbuf[0][w];
      t1 += rbuf[1][w];
    }
    const int bank = (int)(blockIdx.x & (NBANKS - 1));
    const int o2 = (isPred ? 0 : 2);
    atomicAdd(&sums[bank * BANK_STRIDE + o2], (double)t0);
    atomicAdd(&sums[bank * BANK_STRIDE + o2 + 1], (double)t1);
  }
}

__global__ void cl_finalize_kernel(const double* __restrict__ sums,
                                   float* __restrict__ out) {
  double s[4] = {0.0, 0.0, 0.0, 0.0};
  for (int b = 0; b < NBANKS; ++b)
    for (int j = 0; j < 4; ++j) s[j] += sums[b * BANK_STRIDE + j];
  double tprec = (s[1] + 1.0) / (s[0] + 1.0);
  double tsens = (s[3] + 1.0) / (s[2] + 1.0);
  double cl = 2.0 * tprec * tsens / (tprec + tsens + 1e-7);
  out[0] = (float)(1.0 - cl);
}

extern "C" void kernel_launch(void* const* d_in, const int* in_sizes, int n_in,
                              void* d_out, int out_size, void* d_ws,
                              size_t ws_size, hipStream_t stream) {
  const float* pred = (const float*)d_in[0];
  const float* target = (const float*)d_in[1];
  double* sums = (double*)d_ws;
  const int batch = in_sizes[0] / (H * W);  // 32

  hipMemsetAsync(d_ws, 0, NBANKS * BANK_STRIDE * sizeof(double), stream);
  dim3 grid(TPD * TPD, batch, 2);
  cl_skel_kernel<<<grid, NT, 0, stream>>>(pred, target, sums);
  cl_finalize_kernel<<<1, 1, 0, stream>>>(sums, (float*)d_out);
}